// Round 7
// baseline (1465.786 us; speedup 1.0000x reference)
//
#include <hip/hip_runtime.h>
#include <hip/hip_bf16.h>

#define D 64
#define NEG_SLOPE 0.2f
#define EPS 1e-12f
#define CB 9                 // coarse bucket bits: 512 rows per bucket
#define CROWS (1 << CB)
#define NBC_MAX 1024         // supports N <= 524288
#define TILE_E 8192

__device__ __forceinline__ unsigned short f32_to_bf16(float f) {
  unsigned b = __float_as_uint(f);
  return (unsigned short)((b + 0x7FFF + ((b >> 16) & 1)) >> 16);
}

// ===========================================================================
// CSR build, write-amp-free: tile-ranked scatter into coarse buckets,
// then per-bucket counting sort by local row.
// ===========================================================================

__global__ __launch_bounds__(256) void hist_coarse(const int* __restrict__ rows,
                                                   int* __restrict__ bcount,
                                                   int nnz, int nbc) {
  __shared__ int h[NBC_MAX];
  for (int i = threadIdx.x; i < nbc; i += 256) h[i] = 0;
  __syncthreads();
  for (int k = blockIdx.x * 256 + threadIdx.x; k < nnz; k += gridDim.x * 256)
    atomicAdd(&h[rows[k] >> CB], 1);
  __syncthreads();
  for (int i = threadIdx.x; i < nbc; i += 256)
    if (h[i]) atomicAdd(&bcount[i], h[i]);
}

// Single block: exclusive scan of nbc (<=1024) counts -> bbase, bcursor.
#define SCAN_E2 4
__global__ __launch_bounds__(256) void scan_buckets(
    const int* __restrict__ bcount, int* __restrict__ bbase,
    int* __restrict__ bcursor, int nbc, int nnz, int* __restrict__ row_ptr,
    int N) {
  __shared__ int sums[256];
  int base = threadIdx.x * SCAN_E2;
  int c[SCAN_E2];
  int tsum = 0;
#pragma unroll
  for (int i = 0; i < SCAN_E2; i++) {
    int idx = base + i;
    c[i] = (idx < nbc) ? bcount[idx] : 0;
    tsum += c[i];
  }
  sums[threadIdx.x] = tsum;
  __syncthreads();
  for (int off = 1; off < 256; off <<= 1) {
    int t = (threadIdx.x >= off) ? sums[threadIdx.x - off] : 0;
    __syncthreads();
    sums[threadIdx.x] += t;
    __syncthreads();
  }
  int run = sums[threadIdx.x] - tsum;
#pragma unroll
  for (int i = 0; i < SCAN_E2; i++) {
    int idx = base + i;
    if (idx < nbc) {
      bbase[idx] = run;
      bcursor[idx] = run;
    }
    run += c[i];
  }
  if (threadIdx.x == 255) {
    bbase[nbc] = sums[255];
    row_ptr[N] = nnz;
  }
}

// Per-tile: LDS hist -> one global claim per (tile,bucket) -> ranked write.
// Each bucket gets block-contiguous runs => cache lines complete within one
// XCD's L2 => no write amplification.
__global__ __launch_bounds__(256) void scatter_ranked(
    const int* __restrict__ rows, const int* __restrict__ cols,
    const float* __restrict__ vals, int* __restrict__ bcursor,
    int2* __restrict__ bucketed, int nnz, int nbc) {
  __shared__ int h[NBC_MAX];
  int ntiles = (nnz + TILE_E - 1) / TILE_E;
  for (int tile = blockIdx.x; tile < ntiles; tile += gridDim.x) {
    int s = tile * TILE_E;
    int e = min(s + TILE_E, nnz);
    for (int i = threadIdx.x; i < nbc; i += 256) h[i] = 0;
    __syncthreads();
    for (int k = s + threadIdx.x; k < e; k += 256)
      atomicAdd(&h[rows[k] >> CB], 1);
    __syncthreads();
    for (int i = threadIdx.x; i < nbc; i += 256) {
      int c = h[i];
      h[i] = c ? atomicAdd(&bcursor[i], c) : 0;
    }
    __syncthreads();
    for (int k = s + threadIdx.x; k < e; k += 256) {
      int r = rows[k];
      int pos = atomicAdd(&h[r >> CB], 1);
      bucketed[pos] =
          make_int2(cols[k] | ((r & (CROWS - 1)) << 20), __float_as_int(vals[k]));
    }
    __syncthreads();
  }
}

// One block per coarse bucket: counting sort by local row (512 counters).
__global__ __launch_bounds__(256) void sort_csr(
    const int2* __restrict__ bucketed, const int* __restrict__ bbase,
    int* __restrict__ row_ptr, int2* __restrict__ pairs, int N) {
  __shared__ int lhist[CROWS];
  __shared__ int sums[256];
  int b = blockIdx.x;
  int s = bbase[b];
  int e = bbase[b + 1];
  int t = threadIdx.x;
  for (int i = t; i < CROWS; i += 256) lhist[i] = 0;
  __syncthreads();
  for (int k = s + t; k < e; k += 256)
    atomicAdd(&lhist[(unsigned)bucketed[k].x >> 20], 1);
  __syncthreads();
  int c0 = lhist[2 * t];
  int c1 = lhist[2 * t + 1];
  int tsum = c0 + c1;
  sums[t] = tsum;
  __syncthreads();
  for (int off = 1; off < 256; off <<= 1) {
    int v = (t >= off) ? sums[t - off] : 0;
    __syncthreads();
    sums[t] += v;
    __syncthreads();
  }
  int run = sums[t] - tsum;
  int base0 = s + run;
  int base1 = base0 + c0;
  lhist[2 * t] = base0;
  lhist[2 * t + 1] = base1;
  int grow = (b << CB) + 2 * t;
  if (grow < N) row_ptr[grow] = base0;
  if (grow + 1 < N) row_ptr[grow + 1] = base1;
  __syncthreads();
  for (int k = s + t; k < e; k += 256) {
    int2 g = bucketed[k];
    int lr = (unsigned)g.x >> 20;
    int dst = atomicAdd(&lhist[lr], 1);
    pairs[dst] = make_int2(g.x & 0xFFFFF, g.y);
  }
}

// ===========================================================================
// init: ego = concat(user_emb, item_emb) [+ bf16 mirror], single pass
// ===========================================================================
__global__ __launch_bounds__(256) void init_ego(
    const float* __restrict__ user_emb, const float* __restrict__ item_emb,
    float* __restrict__ ego, unsigned short* __restrict__ ego16,
    int nU4, int nT4, int w16) {
  int i = blockIdx.x * 256 + threadIdx.x;
  if (i >= nT4) return;
  float4 v = (i < nU4) ? ((const float4*)user_emb)[i]
                       : ((const float4*)item_emb)[i - nU4];
  ((float4*)ego)[i] = v;
  if (w16) {
    ushort4 o;
    o.x = f32_to_bf16(v.x);
    o.y = f32_to_bf16(v.y);
    o.z = f32_to_bf16(v.z);
    o.w = f32_to_bf16(v.w);
    ((ushort4*)ego16)[i] = o;
  }
}

// ===========================================================================
// SpMM gather v2 (verified 153 us; structural ceiling ~2.85 TB/s random-
// gather confirmed by 3 null/negative concurrency experiments r3/r6).
// One wave per row; 4 lane-groups x 16 lanes; 16 edges per iteration.
// ===========================================================================
__global__ __launch_bounds__(256) void spmm_gather_bf16(
    const int* __restrict__ row_ptr, const int2* __restrict__ pairs,
    const unsigned short* __restrict__ ego16, float* __restrict__ side, int N) {
  int wave = threadIdx.x >> 6;
  int lane = threadIdx.x & 63;
  int g = lane >> 4;                     // edge slot within a 4-edge step
  int l = lane & 15;                     // dim quarter: dims [4l, 4l+4)
  unsigned lofs = (unsigned)(l << 2);    // offset in ushorts within a row
  int w = blockIdx.x * 4 + wave;
  int stride = gridDim.x * 4;
  for (int n = w; n < N; n += stride) {
    int s = row_ptr[n];
    int e = row_ptr[n + 1];
    float a0 = 0.f, a1 = 0.f, a2 = 0.f, a3 = 0.f;
    float b0 = 0.f, b1 = 0.f, b2 = 0.f, b3 = 0.f;
    for (int k = s; k < e; k += 16) {
      int lim = e - 1;
      int k0 = k + g, k1 = k0 + 4, k2 = k0 + 8, k3 = k0 + 12;
      int2 p0 = pairs[min(k0, lim)];
      int2 p1 = pairs[min(k1, lim)];
      int2 p2 = pairs[min(k2, lim)];
      int2 p3 = pairs[min(k3, lim)];
      unsigned o0 = ((unsigned)p0.x << 6) + lofs;
      unsigned o1 = ((unsigned)p1.x << 6) + lofs;
      unsigned o2 = ((unsigned)p2.x << 6) + lofs;
      unsigned o3 = ((unsigned)p3.x << 6) + lofs;
      ushort4 x0 = *(const ushort4*)(ego16 + o0);
      ushort4 x1 = *(const ushort4*)(ego16 + o1);
      ushort4 x2 = *(const ushort4*)(ego16 + o2);
      ushort4 x3 = *(const ushort4*)(ego16 + o3);
      float v0 = (k0 < e) ? __int_as_float(p0.y) : 0.f;
      float v1 = (k1 < e) ? __int_as_float(p1.y) : 0.f;
      float v2 = (k2 < e) ? __int_as_float(p2.y) : 0.f;
      float v3 = (k3 < e) ? __int_as_float(p3.y) : 0.f;
      a0 = fmaf(v0, __uint_as_float((unsigned)x0.x << 16), a0);
      a1 = fmaf(v0, __uint_as_float((unsigned)x0.y << 16), a1);
      a2 = fmaf(v0, __uint_as_float((unsigned)x0.z << 16), a2);
      a3 = fmaf(v0, __uint_as_float((unsigned)x0.w << 16), a3);
      b0 = fmaf(v1, __uint_as_float((unsigned)x1.x << 16), b0);
      b1 = fmaf(v1, __uint_as_float((unsigned)x1.y << 16), b1);
      b2 = fmaf(v1, __uint_as_float((unsigned)x1.z << 16), b2);
      b3 = fmaf(v1, __uint_as_float((unsigned)x1.w << 16), b3);
      a0 = fmaf(v2, __uint_as_float((unsigned)x2.x << 16), a0);
      a1 = fmaf(v2, __uint_as_float((unsigned)x2.y << 16), a1);
      a2 = fmaf(v2, __uint_as_float((unsigned)x2.z << 16), a2);
      a3 = fmaf(v2, __uint_as_float((unsigned)x2.w << 16), a3);
      b0 = fmaf(v3, __uint_as_float((unsigned)x3.x << 16), b0);
      b1 = fmaf(v3, __uint_as_float((unsigned)x3.y << 16), b1);
      b2 = fmaf(v3, __uint_as_float((unsigned)x3.z << 16), b2);
      b3 = fmaf(v3, __uint_as_float((unsigned)x3.w << 16), b3);
    }
    a0 += b0; a1 += b1; a2 += b2; a3 += b3;
    a0 += __shfl_xor(a0, 16);
    a1 += __shfl_xor(a1, 16);
    a2 += __shfl_xor(a2, 16);
    a3 += __shfl_xor(a3, 16);
    a0 += __shfl_xor(a0, 32);
    a1 += __shfl_xor(a1, 32);
    a2 += __shfl_xor(a2, 32);
    a3 += __shfl_xor(a3, 32);
    if (g == 0) {
      ((float4*)(side + ((size_t)n << 6)))[l] = make_float4(a0, a1, a2, a3);
    }
  }
}

__global__ __launch_bounds__(256) void spmm_gather_packed(
    const int* __restrict__ row_ptr, const int2* __restrict__ pairs,
    const float* __restrict__ ego, float* __restrict__ side, int N) {
  int wave = threadIdx.x >> 6;
  int lane = threadIdx.x & 63;
  int w = blockIdx.x * 4 + wave;
  int stride = gridDim.x * 4;
  for (int n = w; n < N; n += stride) {
    int s = row_ptr[n];
    int e = row_ptr[n + 1];
    float acc = 0.f;
    int k = s;
    for (; k + 3 < e; k += 4) {
      int2 p0 = pairs[k], p1 = pairs[k + 1], p2 = pairs[k + 2], p3 = pairs[k + 3];
      float x0 = ego[(size_t)p0.x * D + lane];
      float x1 = ego[(size_t)p1.x * D + lane];
      float x2 = ego[(size_t)p2.x * D + lane];
      float x3 = ego[(size_t)p3.x * D + lane];
      acc = fmaf(__int_as_float(p0.y), x0, acc);
      acc = fmaf(__int_as_float(p1.y), x1, acc);
      acc = fmaf(__int_as_float(p2.y), x2, acc);
      acc = fmaf(__int_as_float(p3.y), x3, acc);
    }
    for (; k < e; k++) {
      int2 p = pairs[k];
      acc = fmaf(__int_as_float(p.y), ego[(size_t)p.x * D + lane], acc);
    }
    side[(size_t)n * D + lane] = acc;
  }
}

// ===========================================================================
// Fallback atomic scatter (only if ws too small / N too big for CSR path)
// ===========================================================================
__global__ __launch_bounds__(256) void scatter_spmm(
    const int* __restrict__ rows, const int* __restrict__ cols,
    const float* __restrict__ vals, const float* __restrict__ ego,
    float* __restrict__ side, int nnz) {
  long long t = (long long)blockIdx.x * blockDim.x + threadIdx.x;
  int e = (int)(t >> 4);
  if (e >= nnz) return;
  int c4 = (int)(t & 15);
  int r = rows[e];
  int c = cols[e];
  float v = vals[e];
  const float4* src = (const float4*)(ego + (size_t)c * D);
  float4 x = src[c4];
  float* dst = side + (size_t)r * D + c4 * 4;
  atomicAdd(dst + 0, v * x.x);
  atomicAdd(dst + 1, v * x.y);
  atomicAdd(dst + 2, v * x.z);
  atomicAdd(dst + 3, v * x.w);
}

// ===========================================================================
// Per-node transform v5: register-W (v3) + TWO nodes per wave.
// Two independent {LDS-write -> broadcast-read -> FMA-chain} streams per
// wave hide the DS-broadcast latency that bounded v3 (one serial chain at
// 2-3 waves/SIMD). Per-node FMA order identical to v3 -> bit-stable.
// ===========================================================================
__global__ __launch_bounds__(256, 2) void transform_nodes(
    float* __restrict__ ego, const float* __restrict__ side,
    const float* __restrict__ Wgc, const float* __restrict__ bgc,
    const float* __restrict__ Wbi, const float* __restrict__ bbi,
    unsigned short* __restrict__ ego16, int w16, int N) {
  __shared__ float sSP[4][2][2 * D];   // [wave][node][{s,p} interleaved]

  int wave = threadIdx.x >> 6;
  int lane = threadIdx.x & 63;

  // W columns -> registers (coalesced loads, L2-hot after first block)
  float wg[D], wb[D];
#pragma unroll
  for (int i = 0; i < D; i++) {
    wg[i] = Wgc[i * D + lane];
    wb[i] = Wbi[i * D + lane];
  }
  float bg = bgc[lane];
  float bb = bbi[lane];

  int waveGlobal = blockIdx.x * 4 + wave;
  int nWaves = gridDim.x * 4;

  float2* sp0 = (float2*)sSP[wave][0];
  float2* sp1 = (float2*)sSP[wave][1];
  const float4* q0 = (const float4*)sSP[wave][0];
  const float4* q1 = (const float4*)sSP[wave][1];

  int n0 = waveGlobal * 2;
  int step = nWaves * 2;
  float s0 = 0.f, e0 = 0.f, s1 = 0.f, e1 = 0.f;
  if (n0 < N) {
    s0 = side[(size_t)n0 * D + lane];
    e0 = ego[(size_t)n0 * D + lane];
  }
  if (n0 + 1 < N) {
    s1 = side[(size_t)(n0 + 1) * D + lane];
    e1 = ego[(size_t)(n0 + 1) * D + lane];
  }
  for (; n0 < N; n0 += step) {
    int n1 = n0 + 1;
    sp0[lane] = make_float2(s0, e0 * s0);
    sp1[lane] = make_float2(s1, e1 * s1);
    // prefetch next node pair while this pair computes
    int m0 = n0 + step, m1 = m0 + 1;
    float sN0 = 0.f, eN0 = 0.f, sN1 = 0.f, eN1 = 0.f;
    if (m0 < N) {
      sN0 = side[(size_t)m0 * D + lane];
      eN0 = ego[(size_t)m0 * D + lane];
    }
    if (m1 < N) {
      sN1 = side[(size_t)m1 * D + lane];
      eN1 = ego[(size_t)m1 * D + lane];
    }
    float ag0 = bg, ab0 = bb;
    float ag1 = 0.f, ab1 = 0.f, ag2 = 0.f, ab2 = 0.f, ag3 = 0.f, ab3 = 0.f;
    float cg0 = bg, cb0 = bb;
    float cg1 = 0.f, cb1 = 0.f, cg2 = 0.f, cb2 = 0.f, cg3 = 0.f, cb3 = 0.f;
#pragma unroll
    for (int j = 0; j < D / 2; j += 2) {
      float4 p0 = q0[j];       // node0 broadcast {s,p} x2 dims
      float4 p1 = q0[j + 1];
      float4 r0 = q1[j];       // node1
      float4 r1 = q1[j + 1];
      ag0 = fmaf(p0.x, wg[2 * j], ag0);
      ab0 = fmaf(p0.y, wb[2 * j], ab0);
      ag1 = fmaf(p0.z, wg[2 * j + 1], ag1);
      ab1 = fmaf(p0.w, wb[2 * j + 1], ab1);
      ag2 = fmaf(p1.x, wg[2 * j + 2], ag2);
      ab2 = fmaf(p1.y, wb[2 * j + 2], ab2);
      ag3 = fmaf(p1.z, wg[2 * j + 3], ag3);
      ab3 = fmaf(p1.w, wb[2 * j + 3], ab3);
      cg0 = fmaf(r0.x, wg[2 * j], cg0);
      cb0 = fmaf(r0.y, wb[2 * j], cb0);
      cg1 = fmaf(r0.z, wg[2 * j + 1], cg1);
      cb1 = fmaf(r0.w, wb[2 * j + 1], cb1);
      cg2 = fmaf(r1.x, wg[2 * j + 2], cg2);
      cb2 = fmaf(r1.y, wb[2 * j + 2], cb2);
      cg3 = fmaf(r1.z, wg[2 * j + 3], cg3);
      cb3 = fmaf(r1.w, wb[2 * j + 3], cb3);
    }
    float v0 = (ag0 + ag1 + ag2 + ag3) + (ab0 + ab1 + ab2 + ab3);
    v0 = v0 > 0.f ? v0 : NEG_SLOPE * v0;
    ego[(size_t)n0 * D + lane] = v0;
    if (w16) ego16[(size_t)n0 * D + lane] = f32_to_bf16(v0);
    if (n1 < N) {
      float v1 = (cg0 + cg1 + cg2 + cg3) + (cb0 + cb1 + cb2 + cb3);
      v1 = v1 > 0.f ? v1 : NEG_SLOPE * v1;
      ego[(size_t)n1 * D + lane] = v1;
      if (w16) ego16[(size_t)n1 * D + lane] = f32_to_bf16(v1);
    }
    s0 = sN0; e0 = eN0; s1 = sN1; e1 = eN1;
  }
}

// ===========================================================================
// Gather one 64-wide slice of the three outputs into d_out
// ===========================================================================
__global__ __launch_bounds__(256) void gather_out(
    const float* __restrict__ ego, const int* __restrict__ u,
    const int* __restrict__ iidx, const int* __restrict__ jidx,
    float* __restrict__ out, int n_users, int B, int slice, int normalize) {
  int r = blockIdx.x * 4 + (threadIdx.x >> 6);
  int lane = threadIdx.x & 63;
  if (r >= 3 * B) return;
  int which = r / B;
  int b = r - which * B;
  int n = (which == 0) ? u[b] : (n_users + ((which == 1) ? iidx[b] : jidx[b]));
  float v = ego[(size_t)n * D + lane];
  if (normalize) {
    float sq = v * v;
#pragma unroll
    for (int off = 32; off > 0; off >>= 1) sq += __shfl_xor(sq, off);
    float norm = sqrtf(sq);
    v = v / fmaxf(norm, EPS);
  }
  out[(size_t)which * B * 256 + (size_t)b * 256 + slice * D + lane] = v;
}

// ===========================================================================
// Launch
// ===========================================================================
extern "C" void kernel_launch(void* const* d_in, const int* in_sizes, int n_in,
                              void* d_out, int out_size, void* d_ws, size_t ws_size,
                              hipStream_t stream) {
  const int*   rows     = (const int*)d_in[0];
  const int*   cols     = (const int*)d_in[1];
  const float* vals     = (const float*)d_in[2];
  const float* user_emb = (const float*)d_in[3];
  const float* item_emb = (const float*)d_in[4];
  const float* W_gc     = (const float*)d_in[5];
  const float* b_gc     = (const float*)d_in[6];
  const float* W_bi     = (const float*)d_in[7];
  const float* b_bi     = (const float*)d_in[8];
  const int*   u        = (const int*)d_in[9];
  const int*   iidx     = (const int*)d_in[10];
  const int*   jidx     = (const int*)d_in[11];

  int nnz     = in_sizes[0];
  int n_users = in_sizes[3] / D;
  int n_items = in_sizes[4] / D;
  int N       = n_users + n_items;
  int B       = in_sizes[9];
  float* out  = (float*)d_out;

  int nbc = (N + CROWS - 1) >> CB;

  // ---- workspace layout ----
  auto align256 = [](size_t x) { return (x + 255) & ~(size_t)255; };
  char* p = (char*)d_ws;
  size_t egoBytes  = align256((size_t)N * D * sizeof(float));
  size_t sideBytes = align256((size_t)N * D * sizeof(float));
  if ((size_t)nnz * sizeof(int2) > sideBytes)
    sideBytes = align256((size_t)nnz * sizeof(int2));  // bucketed aliases side

  float* ego  = (float*)p; p += egoBytes;
  float* side = (float*)p;
  int2* bucketed = (int2*)side;  // alias: dead before first spmm use of side
  p += sideBytes;
  int* row_ptr = (int*)p; p += align256((size_t)(N + 1) * sizeof(int));
  int* bcount  = (int*)p; p += align256((size_t)(nbc + 1) * sizeof(int));
  int* bbase   = (int*)p; p += align256((size_t)(nbc + 1) * sizeof(int));
  int* bcursor = (int*)p; p += align256((size_t)(nbc + 1) * sizeof(int));
  int2* pairs  = (int2*)p; p += align256((size_t)nnz * sizeof(int2));
  size_t need_csr = (size_t)(p - (char*)d_ws);
  unsigned short* ego16 = (unsigned short*)p;
  p += align256((size_t)N * D * sizeof(unsigned short));
  size_t need_16 = (size_t)(p - (char*)d_ws);

  int mode  = (ws_size >= need_csr && N <= (1 << 20) && nbc <= NBC_MAX) ? 0 : 2;
  int use16 = (mode == 0 && ws_size >= need_16) ? 1 : 0;

  // ego = concat(user_emb, item_emb) (+ bf16 mirror) in one pass
  int nU4 = n_users * D / 4;
  int nT4 = N * D / 4;
  init_ego<<<(nT4 + 255) / 256, 256, 0, stream>>>(user_emb, item_emb, ego,
                                                  ego16, nU4, nT4, use16);

  if (mode == 0) {
    hipMemsetAsync(bcount, 0, (size_t)nbc * sizeof(int), stream);
    hist_coarse<<<256, 256, 0, stream>>>(rows, bcount, nnz, nbc);
    scan_buckets<<<1, 256, 0, stream>>>(bcount, bbase, bcursor, nbc, nnz,
                                        row_ptr, N);
    int ntiles = (nnz + TILE_E - 1) / TILE_E;
    scatter_ranked<<<ntiles, 256, 0, stream>>>(rows, cols, vals, bcursor,
                                               bucketed, nnz, nbc);
    sort_csr<<<nbc, 256, 0, stream>>>(bucketed, bbase, row_ptr, pairs, N);
  }

  // slice 0: raw embeddings
  int gblocks = (3 * B + 3) / 4;
  gather_out<<<gblocks, 256, 0, stream>>>(ego, u, iidx, jidx, out, n_users, B,
                                          0, 0);

  long long sthreads = (long long)nnz * 16;
  int sblocks = (int)((sthreads + 255) / 256);

  for (int k = 0; k < 3; k++) {
    if (mode == 0) {
      if (use16)
        spmm_gather_bf16<<<4096, 256, 0, stream>>>(row_ptr, pairs, ego16, side,
                                                   N);
      else
        spmm_gather_packed<<<4096, 256, 0, stream>>>(row_ptr, pairs, ego, side,
                                                     N);
    } else {
      hipMemsetAsync(side, 0, (size_t)N * D * sizeof(float), stream);
      scatter_spmm<<<sblocks, 256, 0, stream>>>(rows, cols, vals, ego, side,
                                                nnz);
    }
    transform_nodes<<<2048, 256, 0, stream>>>(
        ego, side, W_gc + (size_t)k * D * D, b_gc + (size_t)k * D,
        W_bi + (size_t)k * D * D, b_bi + (size_t)k * D, ego16, use16, N);
    gather_out<<<gblocks, 256, 0, stream>>>(ego, u, iidx, jidx, out, n_users,
                                            B, k + 1, 1);
  }
}

// Round 8
// 1069.318 us; speedup vs baseline: 1.3708x; 1.3708x over previous
//
#include <hip/hip_runtime.h>
#include <hip/hip_bf16.h>

#define D 64
#define NEG_SLOPE 0.2f
#define EPS 1e-12f
#define CB 9                 // coarse bucket bits: 512 rows per bucket
#define CROWS (1 << CB)
#define NBC_MAX 1024         // supports N <= 524288
#define TILE_E 8192

__device__ __forceinline__ unsigned short f32_to_bf16(float f) {
  unsigned b = __float_as_uint(f);
  return (unsigned short)((b + 0x7FFF + ((b >> 16) & 1)) >> 16);
}

// ===========================================================================
// CSR build, write-amp-free: tile-ranked scatter into coarse buckets,
// then per-bucket counting sort by local row.
// ===========================================================================

__global__ __launch_bounds__(256) void hist_coarse(const int* __restrict__ rows,
                                                   int* __restrict__ bcount,
                                                   int nnz, int nbc) {
  __shared__ int h[NBC_MAX];
  for (int i = threadIdx.x; i < nbc; i += 256) h[i] = 0;
  __syncthreads();
  for (int k = blockIdx.x * 256 + threadIdx.x; k < nnz; k += gridDim.x * 256)
    atomicAdd(&h[rows[k] >> CB], 1);
  __syncthreads();
  for (int i = threadIdx.x; i < nbc; i += 256)
    if (h[i]) atomicAdd(&bcount[i], h[i]);
}

// Single block: exclusive scan of nbc (<=1024) counts -> bbase, bcursor.
#define SCAN_E2 4
__global__ __launch_bounds__(256) void scan_buckets(
    const int* __restrict__ bcount, int* __restrict__ bbase,
    int* __restrict__ bcursor, int nbc, int nnz, int* __restrict__ row_ptr,
    int N) {
  __shared__ int sums[256];
  int base = threadIdx.x * SCAN_E2;
  int c[SCAN_E2];
  int tsum = 0;
#pragma unroll
  for (int i = 0; i < SCAN_E2; i++) {
    int idx = base + i;
    c[i] = (idx < nbc) ? bcount[idx] : 0;
    tsum += c[i];
  }
  sums[threadIdx.x] = tsum;
  __syncthreads();
  for (int off = 1; off < 256; off <<= 1) {
    int t = (threadIdx.x >= off) ? sums[threadIdx.x - off] : 0;
    __syncthreads();
    sums[threadIdx.x] += t;
    __syncthreads();
  }
  int run = sums[threadIdx.x] - tsum;
#pragma unroll
  for (int i = 0; i < SCAN_E2; i++) {
    int idx = base + i;
    if (idx < nbc) {
      bbase[idx] = run;
      bcursor[idx] = run;
    }
    run += c[i];
  }
  if (threadIdx.x == 255) {
    bbase[nbc] = sums[255];
    row_ptr[N] = nnz;
  }
}

// Per-tile: LDS hist -> one global claim per (tile,bucket) -> ranked write.
// Each bucket gets block-contiguous runs => cache lines complete within one
// XCD's L2 => no write amplification.
__global__ __launch_bounds__(256) void scatter_ranked(
    const int* __restrict__ rows, const int* __restrict__ cols,
    const float* __restrict__ vals, int* __restrict__ bcursor,
    int2* __restrict__ bucketed, int nnz, int nbc) {
  __shared__ int h[NBC_MAX];
  int ntiles = (nnz + TILE_E - 1) / TILE_E;
  for (int tile = blockIdx.x; tile < ntiles; tile += gridDim.x) {
    int s = tile * TILE_E;
    int e = min(s + TILE_E, nnz);
    for (int i = threadIdx.x; i < nbc; i += 256) h[i] = 0;
    __syncthreads();
    for (int k = s + threadIdx.x; k < e; k += 256)
      atomicAdd(&h[rows[k] >> CB], 1);
    __syncthreads();
    for (int i = threadIdx.x; i < nbc; i += 256) {
      int c = h[i];
      h[i] = c ? atomicAdd(&bcursor[i], c) : 0;
    }
    __syncthreads();
    for (int k = s + threadIdx.x; k < e; k += 256) {
      int r = rows[k];
      int pos = atomicAdd(&h[r >> CB], 1);
      bucketed[pos] =
          make_int2(cols[k] | ((r & (CROWS - 1)) << 20), __float_as_int(vals[k]));
    }
    __syncthreads();
  }
}

// One block per coarse bucket: counting sort by local row (512 counters).
__global__ __launch_bounds__(256) void sort_csr(
    const int2* __restrict__ bucketed, const int* __restrict__ bbase,
    int* __restrict__ row_ptr, int2* __restrict__ pairs, int N) {
  __shared__ int lhist[CROWS];
  __shared__ int sums[256];
  int b = blockIdx.x;
  int s = bbase[b];
  int e = bbase[b + 1];
  int t = threadIdx.x;
  for (int i = t; i < CROWS; i += 256) lhist[i] = 0;
  __syncthreads();
  for (int k = s + t; k < e; k += 256)
    atomicAdd(&lhist[(unsigned)bucketed[k].x >> 20], 1);
  __syncthreads();
  int c0 = lhist[2 * t];
  int c1 = lhist[2 * t + 1];
  int tsum = c0 + c1;
  sums[t] = tsum;
  __syncthreads();
  for (int off = 1; off < 256; off <<= 1) {
    int v = (t >= off) ? sums[t - off] : 0;
    __syncthreads();
    sums[t] += v;
    __syncthreads();
  }
  int run = sums[t] - tsum;
  int base0 = s + run;
  int base1 = base0 + c0;
  lhist[2 * t] = base0;
  lhist[2 * t + 1] = base1;
  int grow = (b << CB) + 2 * t;
  if (grow < N) row_ptr[grow] = base0;
  if (grow + 1 < N) row_ptr[grow + 1] = base1;
  __syncthreads();
  for (int k = s + t; k < e; k += 256) {
    int2 g = bucketed[k];
    int lr = (unsigned)g.x >> 20;
    int dst = atomicAdd(&lhist[lr], 1);
    pairs[dst] = make_int2(g.x & 0xFFFFF, g.y);
  }
}

// ===========================================================================
// init: ego = concat(user_emb, item_emb) [+ bf16 mirror], single pass
// ===========================================================================
__global__ __launch_bounds__(256) void init_ego(
    const float* __restrict__ user_emb, const float* __restrict__ item_emb,
    float* __restrict__ ego, unsigned short* __restrict__ ego16,
    int nU4, int nT4, int w16) {
  int i = blockIdx.x * 256 + threadIdx.x;
  if (i >= nT4) return;
  float4 v = (i < nU4) ? ((const float4*)user_emb)[i]
                       : ((const float4*)item_emb)[i - nU4];
  ((float4*)ego)[i] = v;
  if (w16) {
    ushort4 o;
    o.x = f32_to_bf16(v.x);
    o.y = f32_to_bf16(v.y);
    o.z = f32_to_bf16(v.z);
    o.w = f32_to_bf16(v.w);
    ((ushort4*)ego16)[i] = o;
  }
}

// ===========================================================================
// SpMM gather v2 (verified 153 us; structural ceiling ~2.85 TB/s random-
// gather confirmed by 3 null/negative concurrency experiments r3/r6).
// One wave per row; 4 lane-groups x 16 lanes; 16 edges per iteration.
// ===========================================================================
__global__ __launch_bounds__(256) void spmm_gather_bf16(
    const int* __restrict__ row_ptr, const int2* __restrict__ pairs,
    const unsigned short* __restrict__ ego16, float* __restrict__ side, int N) {
  int wave = threadIdx.x >> 6;
  int lane = threadIdx.x & 63;
  int g = lane >> 4;                     // edge slot within a 4-edge step
  int l = lane & 15;                     // dim quarter: dims [4l, 4l+4)
  unsigned lofs = (unsigned)(l << 2);    // offset in ushorts within a row
  int w = blockIdx.x * 4 + wave;
  int stride = gridDim.x * 4;
  for (int n = w; n < N; n += stride) {
    int s = row_ptr[n];
    int e = row_ptr[n + 1];
    float a0 = 0.f, a1 = 0.f, a2 = 0.f, a3 = 0.f;
    float b0 = 0.f, b1 = 0.f, b2 = 0.f, b3 = 0.f;
    for (int k = s; k < e; k += 16) {
      int lim = e - 1;
      int k0 = k + g, k1 = k0 + 4, k2 = k0 + 8, k3 = k0 + 12;
      int2 p0 = pairs[min(k0, lim)];
      int2 p1 = pairs[min(k1, lim)];
      int2 p2 = pairs[min(k2, lim)];
      int2 p3 = pairs[min(k3, lim)];
      unsigned o0 = ((unsigned)p0.x << 6) + lofs;
      unsigned o1 = ((unsigned)p1.x << 6) + lofs;
      unsigned o2 = ((unsigned)p2.x << 6) + lofs;
      unsigned o3 = ((unsigned)p3.x << 6) + lofs;
      ushort4 x0 = *(const ushort4*)(ego16 + o0);
      ushort4 x1 = *(const ushort4*)(ego16 + o1);
      ushort4 x2 = *(const ushort4*)(ego16 + o2);
      ushort4 x3 = *(const ushort4*)(ego16 + o3);
      float v0 = (k0 < e) ? __int_as_float(p0.y) : 0.f;
      float v1 = (k1 < e) ? __int_as_float(p1.y) : 0.f;
      float v2 = (k2 < e) ? __int_as_float(p2.y) : 0.f;
      float v3 = (k3 < e) ? __int_as_float(p3.y) : 0.f;
      a0 = fmaf(v0, __uint_as_float((unsigned)x0.x << 16), a0);
      a1 = fmaf(v0, __uint_as_float((unsigned)x0.y << 16), a1);
      a2 = fmaf(v0, __uint_as_float((unsigned)x0.z << 16), a2);
      a3 = fmaf(v0, __uint_as_float((unsigned)x0.w << 16), a3);
      b0 = fmaf(v1, __uint_as_float((unsigned)x1.x << 16), b0);
      b1 = fmaf(v1, __uint_as_float((unsigned)x1.y << 16), b1);
      b2 = fmaf(v1, __uint_as_float((unsigned)x1.z << 16), b2);
      b3 = fmaf(v1, __uint_as_float((unsigned)x1.w << 16), b3);
      a0 = fmaf(v2, __uint_as_float((unsigned)x2.x << 16), a0);
      a1 = fmaf(v2, __uint_as_float((unsigned)x2.y << 16), a1);
      a2 = fmaf(v2, __uint_as_float((unsigned)x2.z << 16), a2);
      a3 = fmaf(v2, __uint_as_float((unsigned)x2.w << 16), a3);
      b0 = fmaf(v3, __uint_as_float((unsigned)x3.x << 16), b0);
      b1 = fmaf(v3, __uint_as_float((unsigned)x3.y << 16), b1);
      b2 = fmaf(v3, __uint_as_float((unsigned)x3.z << 16), b2);
      b3 = fmaf(v3, __uint_as_float((unsigned)x3.w << 16), b3);
    }
    a0 += b0; a1 += b1; a2 += b2; a3 += b3;
    a0 += __shfl_xor(a0, 16);
    a1 += __shfl_xor(a1, 16);
    a2 += __shfl_xor(a2, 16);
    a3 += __shfl_xor(a3, 16);
    a0 += __shfl_xor(a0, 32);
    a1 += __shfl_xor(a1, 32);
    a2 += __shfl_xor(a2, 32);
    a3 += __shfl_xor(a3, 32);
    if (g == 0) {
      ((float4*)(side + ((size_t)n << 6)))[l] = make_float4(a0, a1, a2, a3);
    }
  }
}

__global__ __launch_bounds__(256) void spmm_gather_packed(
    const int* __restrict__ row_ptr, const int2* __restrict__ pairs,
    const float* __restrict__ ego, float* __restrict__ side, int N) {
  int wave = threadIdx.x >> 6;
  int lane = threadIdx.x & 63;
  int w = blockIdx.x * 4 + wave;
  int stride = gridDim.x * 4;
  for (int n = w; n < N; n += stride) {
    int s = row_ptr[n];
    int e = row_ptr[n + 1];
    float acc = 0.f;
    int k = s;
    for (; k + 3 < e; k += 4) {
      int2 p0 = pairs[k], p1 = pairs[k + 1], p2 = pairs[k + 2], p3 = pairs[k + 3];
      float x0 = ego[(size_t)p0.x * D + lane];
      float x1 = ego[(size_t)p1.x * D + lane];
      float x2 = ego[(size_t)p2.x * D + lane];
      float x3 = ego[(size_t)p3.x * D + lane];
      acc = fmaf(__int_as_float(p0.y), x0, acc);
      acc = fmaf(__int_as_float(p1.y), x1, acc);
      acc = fmaf(__int_as_float(p2.y), x2, acc);
      acc = fmaf(__int_as_float(p3.y), x3, acc);
    }
    for (; k < e; k++) {
      int2 p = pairs[k];
      acc = fmaf(__int_as_float(p.y), ego[(size_t)p.x * D + lane], acc);
    }
    side[(size_t)n * D + lane] = acc;
  }
}

// ===========================================================================
// Fallback atomic scatter (only if ws too small / N too big for CSR path)
// ===========================================================================
__global__ __launch_bounds__(256) void scatter_spmm(
    const int* __restrict__ rows, const int* __restrict__ cols,
    const float* __restrict__ vals, const float* __restrict__ ego,
    float* __restrict__ side, int nnz) {
  long long t = (long long)blockIdx.x * blockDim.x + threadIdx.x;
  int e = (int)(t >> 4);
  if (e >= nnz) return;
  int c4 = (int)(t & 15);
  int r = rows[e];
  int c = cols[e];
  float v = vals[e];
  const float4* src = (const float4*)(ego + (size_t)c * D);
  float4 x = src[c4];
  float* dst = side + (size_t)r * D + c4 * 4;
  atomicAdd(dst + 0, v * x.x);
  atomicAdd(dst + 1, v * x.y);
  atomicAdd(dst + 2, v * x.z);
  atomicAdd(dst + 3, v * x.w);
}

// ===========================================================================
// Per-node transform v3 (verified ~76 us): W columns in registers, LDS only
// for the per-node 512 B s/p broadcast vector. Next node's s/e prefetched.
// v5 (2 nodes/wave) REGRESSED 3x: >128 live VGPRs -> compiler capped at 128
// and spilled W to scratch (WRITE_SIZE +28 MB). v3 is the register-pressure
// frontier -- do not add per-wave state.
// ===========================================================================
__global__ __launch_bounds__(256, 2) void transform_nodes(
    float* __restrict__ ego, const float* __restrict__ side,
    const float* __restrict__ Wgc, const float* __restrict__ bgc,
    const float* __restrict__ Wbi, const float* __restrict__ bbi,
    unsigned short* __restrict__ ego16, int w16, int N) {
  __shared__ float sSP[4][2 * D];   // per-wave {s,p} interleaved (512 B/wave)

  int wave = threadIdx.x >> 6;
  int lane = threadIdx.x & 63;

  // W columns -> registers (coalesced loads, L2-hot after first block)
  float wg[D], wb[D];
#pragma unroll
  for (int i = 0; i < D; i++) {
    wg[i] = Wgc[i * D + lane];
    wb[i] = Wbi[i * D + lane];
  }
  float bg = bgc[lane];
  float bb = bbi[lane];

  int waveGlobal = blockIdx.x * 4 + wave;
  int nWaves = gridDim.x * 4;

  float2* spw = (float2*)sSP[wave];
  const float4* q = (const float4*)sSP[wave];

  int n = waveGlobal;
  float s = 0.f, e = 0.f;
  if (n < N) {
    s = side[(size_t)n * D + lane];
    e = ego[(size_t)n * D + lane];
  }
  for (; n < N; n += nWaves) {
    spw[lane] = make_float2(s, e * s);
    // prefetch next node while this node computes
    int nn = n + nWaves;
    float sN = 0.f, eN = 0.f;
    if (nn < N) {
      sN = side[(size_t)nn * D + lane];
      eN = ego[(size_t)nn * D + lane];
    }
    float ag0 = bg, ab0 = bb;
    float ag1 = 0.f, ab1 = 0.f, ag2 = 0.f, ab2 = 0.f, ag3 = 0.f, ab3 = 0.f;
#pragma unroll
    for (int j = 0; j < D / 2; j += 2) {
      float4 p0 = q[j];       // broadcast {s_2j, p_2j, s_2j+1, p_2j+1}
      float4 p1 = q[j + 1];   // broadcast {s_2j+2, p_2j+2, s_2j+3, p_2j+3}
      ag0 = fmaf(p0.x, wg[2 * j], ag0);
      ab0 = fmaf(p0.y, wb[2 * j], ab0);
      ag1 = fmaf(p0.z, wg[2 * j + 1], ag1);
      ab1 = fmaf(p0.w, wb[2 * j + 1], ab1);
      ag2 = fmaf(p1.x, wg[2 * j + 2], ag2);
      ab2 = fmaf(p1.y, wb[2 * j + 2], ab2);
      ag3 = fmaf(p1.z, wg[2 * j + 3], ag3);
      ab3 = fmaf(p1.w, wb[2 * j + 3], ab3);
    }
    float v = (ag0 + ag1 + ag2 + ag3) + (ab0 + ab1 + ab2 + ab3);
    v = v > 0.f ? v : NEG_SLOPE * v;
    ego[(size_t)n * D + lane] = v;
    if (w16) ego16[(size_t)n * D + lane] = f32_to_bf16(v);
    s = sN;
    e = eN;
  }
}

// ===========================================================================
// Gather one 64-wide slice of the three outputs into d_out
// ===========================================================================
__global__ __launch_bounds__(256) void gather_out(
    const float* __restrict__ ego, const int* __restrict__ u,
    const int* __restrict__ iidx, const int* __restrict__ jidx,
    float* __restrict__ out, int n_users, int B, int slice, int normalize) {
  int r = blockIdx.x * 4 + (threadIdx.x >> 6);
  int lane = threadIdx.x & 63;
  if (r >= 3 * B) return;
  int which = r / B;
  int b = r - which * B;
  int n = (which == 0) ? u[b] : (n_users + ((which == 1) ? iidx[b] : jidx[b]));
  float v = ego[(size_t)n * D + lane];
  if (normalize) {
    float sq = v * v;
#pragma unroll
    for (int off = 32; off > 0; off >>= 1) sq += __shfl_xor(sq, off);
    float norm = sqrtf(sq);
    v = v / fmaxf(norm, EPS);
  }
  out[(size_t)which * B * 256 + (size_t)b * 256 + slice * D + lane] = v;
}

// ===========================================================================
// Launch
// ===========================================================================
extern "C" void kernel_launch(void* const* d_in, const int* in_sizes, int n_in,
                              void* d_out, int out_size, void* d_ws, size_t ws_size,
                              hipStream_t stream) {
  const int*   rows     = (const int*)d_in[0];
  const int*   cols     = (const int*)d_in[1];
  const float* vals     = (const float*)d_in[2];
  const float* user_emb = (const float*)d_in[3];
  const float* item_emb = (const float*)d_in[4];
  const float* W_gc     = (const float*)d_in[5];
  const float* b_gc     = (const float*)d_in[6];
  const float* W_bi     = (const float*)d_in[7];
  const float* b_bi     = (const float*)d_in[8];
  const int*   u        = (const int*)d_in[9];
  const int*   iidx     = (const int*)d_in[10];
  const int*   jidx     = (const int*)d_in[11];

  int nnz     = in_sizes[0];
  int n_users = in_sizes[3] / D;
  int n_items = in_sizes[4] / D;
  int N       = n_users + n_items;
  int B       = in_sizes[9];
  float* out  = (float*)d_out;

  int nbc = (N + CROWS - 1) >> CB;

  // ---- workspace layout ----
  auto align256 = [](size_t x) { return (x + 255) & ~(size_t)255; };
  char* p = (char*)d_ws;
  size_t egoBytes  = align256((size_t)N * D * sizeof(float));
  size_t sideBytes = align256((size_t)N * D * sizeof(float));
  if ((size_t)nnz * sizeof(int2) > sideBytes)
    sideBytes = align256((size_t)nnz * sizeof(int2));  // bucketed aliases side

  float* ego  = (float*)p; p += egoBytes;
  float* side = (float*)p;
  int2* bucketed = (int2*)side;  // alias: dead before first spmm use of side
  p += sideBytes;
  int* row_ptr = (int*)p; p += align256((size_t)(N + 1) * sizeof(int));
  int* bcount  = (int*)p; p += align256((size_t)(nbc + 1) * sizeof(int));
  int* bbase   = (int*)p; p += align256((size_t)(nbc + 1) * sizeof(int));
  int* bcursor = (int*)p; p += align256((size_t)(nbc + 1) * sizeof(int));
  int2* pairs  = (int2*)p; p += align256((size_t)nnz * sizeof(int2));
  size_t need_csr = (size_t)(p - (char*)d_ws);
  unsigned short* ego16 = (unsigned short*)p;
  p += align256((size_t)N * D * sizeof(unsigned short));
  size_t need_16 = (size_t)(p - (char*)d_ws);

  int mode  = (ws_size >= need_csr && N <= (1 << 20) && nbc <= NBC_MAX) ? 0 : 2;
  int use16 = (mode == 0 && ws_size >= need_16) ? 1 : 0;

  // ego = concat(user_emb, item_emb) (+ bf16 mirror) in one pass
  int nU4 = n_users * D / 4;
  int nT4 = N * D / 4;
  init_ego<<<(nT4 + 255) / 256, 256, 0, stream>>>(user_emb, item_emb, ego,
                                                  ego16, nU4, nT4, use16);

  if (mode == 0) {
    hipMemsetAsync(bcount, 0, (size_t)nbc * sizeof(int), stream);
    hist_coarse<<<256, 256, 0, stream>>>(rows, bcount, nnz, nbc);
    scan_buckets<<<1, 256, 0, stream>>>(bcount, bbase, bcursor, nbc, nnz,
                                        row_ptr, N);
    int ntiles = (nnz + TILE_E - 1) / TILE_E;
    scatter_ranked<<<ntiles, 256, 0, stream>>>(rows, cols, vals, bcursor,
                                               bucketed, nnz, nbc);
    sort_csr<<<nbc, 256, 0, stream>>>(bucketed, bbase, row_ptr, pairs, N);
  }

  // slice 0: raw embeddings
  int gblocks = (3 * B + 3) / 4;
  gather_out<<<gblocks, 256, 0, stream>>>(ego, u, iidx, jidx, out, n_users, B,
                                          0, 0);

  long long sthreads = (long long)nnz * 16;
  int sblocks = (int)((sthreads + 255) / 256);

  for (int k = 0; k < 3; k++) {
    if (mode == 0) {
      if (use16)
        spmm_gather_bf16<<<2048, 256, 0, stream>>>(row_ptr, pairs, ego16, side,
                                                   N);
      else
        spmm_gather_packed<<<2048, 256, 0, stream>>>(row_ptr, pairs, ego, side,
                                                     N);
    } else {
      hipMemsetAsync(side, 0, (size_t)N * D * sizeof(float), stream);
      scatter_spmm<<<sblocks, 256, 0, stream>>>(rows, cols, vals, ego, side,
                                                nnz);
    }
    // ego16 mirror only needed while another spmm follows (k<2)
    transform_nodes<<<2048, 256, 0, stream>>>(
        ego, side, W_gc + (size_t)k * D * D, b_gc + (size_t)k * D,
        W_bi + (size_t)k * D * D, b_bi + (size_t)k * D, ego16,
        use16 && (k < 2), N);
    gather_out<<<gblocks, 256, 0, stream>>>(ego, u, iidx, jidx, out, n_users,
                                            B, k + 1, 1);
  }
}

// Round 9
// 1014.011 us; speedup vs baseline: 1.4455x; 1.0545x over previous
//
#include <hip/hip_runtime.h>
#include <hip/hip_bf16.h>

#define D 64
#define NEG_SLOPE 0.2f
#define EPS 1e-12f
#define CB 9                 // coarse bucket bits: 512 rows per bucket
#define CROWS (1 << CB)
#define NBC_MAX 1024         // supports N <= 524288
#define TILE_E 8192

__device__ __forceinline__ unsigned short f32_to_bf16(float f) {
  unsigned b = __float_as_uint(f);
  return (unsigned short)((b + 0x7FFF + ((b >> 16) & 1)) >> 16);
}

// ===========================================================================
// CSR build, write-amp-free: tile-ranked scatter into coarse buckets,
// then per-bucket counting sort by local row. Round 9: all per-element
// loads vectorized 2-4x (they were instruction-bound at 4-8 B/load).
// ===========================================================================

__global__ __launch_bounds__(256) void hist_coarse(const int* __restrict__ rows,
                                                   int* __restrict__ bcount,
                                                   int nnz, int nbc) {
  __shared__ int h[NBC_MAX];
  for (int i = threadIdx.x; i < nbc; i += 256) h[i] = 0;
  __syncthreads();
  int nnz4 = nnz >> 2;
  for (int k = blockIdx.x * 256 + threadIdx.x; k < nnz4; k += gridDim.x * 256) {
    int4 r = ((const int4*)rows)[k];
    atomicAdd(&h[r.x >> CB], 1);
    atomicAdd(&h[r.y >> CB], 1);
    atomicAdd(&h[r.z >> CB], 1);
    atomicAdd(&h[r.w >> CB], 1);
  }
  if (blockIdx.x == 0 && threadIdx.x < (nnz & 3))
    atomicAdd(&h[rows[nnz4 * 4 + threadIdx.x] >> CB], 1);
  __syncthreads();
  for (int i = threadIdx.x; i < nbc; i += 256)
    if (h[i]) atomicAdd(&bcount[i], h[i]);
}

// Single block: exclusive scan of nbc (<=1024) counts -> bbase, bcursor.
#define SCAN_E2 4
__global__ __launch_bounds__(256) void scan_buckets(
    const int* __restrict__ bcount, int* __restrict__ bbase,
    int* __restrict__ bcursor, int nbc, int nnz, int* __restrict__ row_ptr,
    int N) {
  __shared__ int sums[256];
  int base = threadIdx.x * SCAN_E2;
  int c[SCAN_E2];
  int tsum = 0;
#pragma unroll
  for (int i = 0; i < SCAN_E2; i++) {
    int idx = base + i;
    c[i] = (idx < nbc) ? bcount[idx] : 0;
    tsum += c[i];
  }
  sums[threadIdx.x] = tsum;
  __syncthreads();
  for (int off = 1; off < 256; off <<= 1) {
    int t = (threadIdx.x >= off) ? sums[threadIdx.x - off] : 0;
    __syncthreads();
    sums[threadIdx.x] += t;
    __syncthreads();
  }
  int run = sums[threadIdx.x] - tsum;
#pragma unroll
  for (int i = 0; i < SCAN_E2; i++) {
    int idx = base + i;
    if (idx < nbc) {
      bbase[idx] = run;
      bcursor[idx] = run;
    }
    run += c[i];
  }
  if (threadIdx.x == 255) {
    bbase[nbc] = sums[255];
    row_ptr[N] = nnz;
  }
}

// Per-tile: LDS hist -> one global claim per (tile,bucket) -> ranked write.
// 2 edges per thread-iteration (tile base is even => int2/float2 aligned).
__global__ __launch_bounds__(256) void scatter_ranked(
    const int* __restrict__ rows, const int* __restrict__ cols,
    const float* __restrict__ vals, int* __restrict__ bcursor,
    int2* __restrict__ bucketed, int nnz, int nbc) {
  __shared__ int h[NBC_MAX];
  int ntiles = (nnz + TILE_E - 1) / TILE_E;
  int t = threadIdx.x;
  for (int tile = blockIdx.x; tile < ntiles; tile += gridDim.x) {
    int s = tile * TILE_E;
    int e = min(s + TILE_E, nnz);
    bool odd = ((e - s) & 1) != 0;
    for (int i = t; i < nbc; i += 256) h[i] = 0;
    __syncthreads();
    for (int k = s + 2 * t; k + 1 < e; k += 512) {
      int2 r2 = *(const int2*)(rows + k);
      atomicAdd(&h[r2.x >> CB], 1);
      atomicAdd(&h[r2.y >> CB], 1);
    }
    if (t == 0 && odd) atomicAdd(&h[rows[e - 1] >> CB], 1);
    __syncthreads();
    for (int i = t; i < nbc; i += 256) {
      int c = h[i];
      h[i] = c ? atomicAdd(&bcursor[i], c) : 0;
    }
    __syncthreads();
    for (int k = s + 2 * t; k + 1 < e; k += 512) {
      int2 r2 = *(const int2*)(rows + k);
      int2 c2 = *(const int2*)(cols + k);
      float2 v2 = *(const float2*)(vals + k);
      int pos0 = atomicAdd(&h[r2.x >> CB], 1);
      bucketed[pos0] = make_int2(c2.x | ((r2.x & (CROWS - 1)) << 20),
                                 __float_as_int(v2.x));
      int pos1 = atomicAdd(&h[r2.y >> CB], 1);
      bucketed[pos1] = make_int2(c2.y | ((r2.y & (CROWS - 1)) << 20),
                                 __float_as_int(v2.y));
    }
    if (t == 0 && odd) {
      int k = e - 1;
      int r = rows[k];
      int pos = atomicAdd(&h[r >> CB], 1);
      bucketed[pos] =
          make_int2(cols[k] | ((r & (CROWS - 1)) << 20), __float_as_int(vals[k]));
    }
    __syncthreads();
  }
}

// One block per coarse bucket: counting sort by local row (512 counters).
// Both passes vectorized 2 edges/iter with odd-prefix/odd-tail handling
// (bucket base bbase[b] can be odd; int4 loads need even int2-index).
__global__ __launch_bounds__(256) void sort_csr(
    const int2* __restrict__ bucketed, const int* __restrict__ bbase,
    int* __restrict__ row_ptr, int2* __restrict__ pairs, int N) {
  __shared__ int lhist[CROWS];
  __shared__ int sums[256];
  int b = blockIdx.x;
  int s = bbase[b];
  int e = bbase[b + 1];
  int t = threadIdx.x;
  int s2 = (s + 1) & ~1;                  // first even index >= s
  bool pre = (s2 > s) && (s < e);         // lone leading element at s
  bool tail = (e > s2) && (((e - s2) & 1) != 0);  // lone trailing at e-1
  for (int i = t; i < CROWS; i += 256) lhist[i] = 0;
  __syncthreads();
  if (t == 0 && pre) atomicAdd(&lhist[(unsigned)bucketed[s].x >> 20], 1);
  for (int k = s2 + 2 * t; k + 1 < e; k += 512) {
    int4 g = *(const int4*)(bucketed + k);
    atomicAdd(&lhist[(unsigned)g.x >> 20], 1);
    atomicAdd(&lhist[(unsigned)g.z >> 20], 1);
  }
  if (t == 0 && tail) atomicAdd(&lhist[(unsigned)bucketed[e - 1].x >> 20], 1);
  __syncthreads();
  int c0 = lhist[2 * t];
  int c1 = lhist[2 * t + 1];
  int tsum = c0 + c1;
  sums[t] = tsum;
  __syncthreads();
  for (int off = 1; off < 256; off <<= 1) {
    int v = (t >= off) ? sums[t - off] : 0;
    __syncthreads();
    sums[t] += v;
    __syncthreads();
  }
  int run = sums[t] - tsum;
  int base0 = s + run;
  int base1 = base0 + c0;
  lhist[2 * t] = base0;
  lhist[2 * t + 1] = base1;
  int grow = (b << CB) + 2 * t;
  if (grow < N) row_ptr[grow] = base0;
  if (grow + 1 < N) row_ptr[grow + 1] = base1;
  __syncthreads();
  if (t == 0 && pre) {
    int2 g = bucketed[s];
    int lr = (unsigned)g.x >> 20;
    int dst = atomicAdd(&lhist[lr], 1);
    pairs[dst] = make_int2(g.x & 0xFFFFF, g.y);
  }
  for (int k = s2 + 2 * t; k + 1 < e; k += 512) {
    int4 g = *(const int4*)(bucketed + k);
    int lr0 = (unsigned)g.x >> 20;
    int d0 = atomicAdd(&lhist[lr0], 1);
    pairs[d0] = make_int2(g.x & 0xFFFFF, g.y);
    int lr1 = (unsigned)g.z >> 20;
    int d1 = atomicAdd(&lhist[lr1], 1);
    pairs[d1] = make_int2(g.z & 0xFFFFF, g.w);
  }
  if (t == 0 && tail) {
    int2 g = bucketed[e - 1];
    int lr = (unsigned)g.x >> 20;
    int dst = atomicAdd(&lhist[lr], 1);
    pairs[dst] = make_int2(g.x & 0xFFFFF, g.y);
  }
}

// ===========================================================================
// init: ego = concat(user_emb, item_emb) [+ bf16 mirror], single pass
// ===========================================================================
__global__ __launch_bounds__(256) void init_ego(
    const float* __restrict__ user_emb, const float* __restrict__ item_emb,
    float* __restrict__ ego, unsigned short* __restrict__ ego16,
    int nU4, int nT4, int w16) {
  int i = blockIdx.x * 256 + threadIdx.x;
  if (i >= nT4) return;
  float4 v = (i < nU4) ? ((const float4*)user_emb)[i]
                       : ((const float4*)item_emb)[i - nU4];
  ((float4*)ego)[i] = v;
  if (w16) {
    ushort4 o;
    o.x = f32_to_bf16(v.x);
    o.y = f32_to_bf16(v.y);
    o.z = f32_to_bf16(v.z);
    o.w = f32_to_bf16(v.w);
    ((ushort4*)ego16)[i] = o;
  }
}

// ===========================================================================
// SpMM gather v2 (verified 153 us; structural ceiling ~2.85 TB/s random-
// gather confirmed by 3 null/negative concurrency experiments r3/r6).
// One wave per row; 4 lane-groups x 16 lanes; 16 edges per iteration.
// ===========================================================================
__global__ __launch_bounds__(256) void spmm_gather_bf16(
    const int* __restrict__ row_ptr, const int2* __restrict__ pairs,
    const unsigned short* __restrict__ ego16, float* __restrict__ side, int N) {
  int wave = threadIdx.x >> 6;
  int lane = threadIdx.x & 63;
  int g = lane >> 4;                     // edge slot within a 4-edge step
  int l = lane & 15;                     // dim quarter: dims [4l, 4l+4)
  unsigned lofs = (unsigned)(l << 2);    // offset in ushorts within a row
  int w = blockIdx.x * 4 + wave;
  int stride = gridDim.x * 4;
  for (int n = w; n < N; n += stride) {
    int s = row_ptr[n];
    int e = row_ptr[n + 1];
    float a0 = 0.f, a1 = 0.f, a2 = 0.f, a3 = 0.f;
    float b0 = 0.f, b1 = 0.f, b2 = 0.f, b3 = 0.f;
    for (int k = s; k < e; k += 16) {
      int lim = e - 1;
      int k0 = k + g, k1 = k0 + 4, k2 = k0 + 8, k3 = k0 + 12;
      int2 p0 = pairs[min(k0, lim)];
      int2 p1 = pairs[min(k1, lim)];
      int2 p2 = pairs[min(k2, lim)];
      int2 p3 = pairs[min(k3, lim)];
      unsigned o0 = ((unsigned)p0.x << 6) + lofs;
      unsigned o1 = ((unsigned)p1.x << 6) + lofs;
      unsigned o2 = ((unsigned)p2.x << 6) + lofs;
      unsigned o3 = ((unsigned)p3.x << 6) + lofs;
      ushort4 x0 = *(const ushort4*)(ego16 + o0);
      ushort4 x1 = *(const ushort4*)(ego16 + o1);
      ushort4 x2 = *(const ushort4*)(ego16 + o2);
      ushort4 x3 = *(const ushort4*)(ego16 + o3);
      float v0 = (k0 < e) ? __int_as_float(p0.y) : 0.f;
      float v1 = (k1 < e) ? __int_as_float(p1.y) : 0.f;
      float v2 = (k2 < e) ? __int_as_float(p2.y) : 0.f;
      float v3 = (k3 < e) ? __int_as_float(p3.y) : 0.f;
      a0 = fmaf(v0, __uint_as_float((unsigned)x0.x << 16), a0);
      a1 = fmaf(v0, __uint_as_float((unsigned)x0.y << 16), a1);
      a2 = fmaf(v0, __uint_as_float((unsigned)x0.z << 16), a2);
      a3 = fmaf(v0, __uint_as_float((unsigned)x0.w << 16), a3);
      b0 = fmaf(v1, __uint_as_float((unsigned)x1.x << 16), b0);
      b1 = fmaf(v1, __uint_as_float((unsigned)x1.y << 16), b1);
      b2 = fmaf(v1, __uint_as_float((unsigned)x1.z << 16), b2);
      b3 = fmaf(v1, __uint_as_float((unsigned)x1.w << 16), b3);
      a0 = fmaf(v2, __uint_as_float((unsigned)x2.x << 16), a0);
      a1 = fmaf(v2, __uint_as_float((unsigned)x2.y << 16), a1);
      a2 = fmaf(v2, __uint_as_float((unsigned)x2.z << 16), a2);
      a3 = fmaf(v2, __uint_as_float((unsigned)x2.w << 16), a3);
      b0 = fmaf(v3, __uint_as_float((unsigned)x3.x << 16), b0);
      b1 = fmaf(v3, __uint_as_float((unsigned)x3.y << 16), b1);
      b2 = fmaf(v3, __uint_as_float((unsigned)x3.z << 16), b2);
      b3 = fmaf(v3, __uint_as_float((unsigned)x3.w << 16), b3);
    }
    a0 += b0; a1 += b1; a2 += b2; a3 += b3;
    a0 += __shfl_xor(a0, 16);
    a1 += __shfl_xor(a1, 16);
    a2 += __shfl_xor(a2, 16);
    a3 += __shfl_xor(a3, 16);
    a0 += __shfl_xor(a0, 32);
    a1 += __shfl_xor(a1, 32);
    a2 += __shfl_xor(a2, 32);
    a3 += __shfl_xor(a3, 32);
    if (g == 0) {
      ((float4*)(side + ((size_t)n << 6)))[l] = make_float4(a0, a1, a2, a3);
    }
  }
}

__global__ __launch_bounds__(256) void spmm_gather_packed(
    const int* __restrict__ row_ptr, const int2* __restrict__ pairs,
    const float* __restrict__ ego, float* __restrict__ side, int N) {
  int wave = threadIdx.x >> 6;
  int lane = threadIdx.x & 63;
  int w = blockIdx.x * 4 + wave;
  int stride = gridDim.x * 4;
  for (int n = w; n < N; n += stride) {
    int s = row_ptr[n];
    int e = row_ptr[n + 1];
    float acc = 0.f;
    int k = s;
    for (; k + 3 < e; k += 4) {
      int2 p0 = pairs[k], p1 = pairs[k + 1], p2 = pairs[k + 2], p3 = pairs[k + 3];
      float x0 = ego[(size_t)p0.x * D + lane];
      float x1 = ego[(size_t)p1.x * D + lane];
      float x2 = ego[(size_t)p2.x * D + lane];
      float x3 = ego[(size_t)p3.x * D + lane];
      acc = fmaf(__int_as_float(p0.y), x0, acc);
      acc = fmaf(__int_as_float(p1.y), x1, acc);
      acc = fmaf(__int_as_float(p2.y), x2, acc);
      acc = fmaf(__int_as_float(p3.y), x3, acc);
    }
    for (; k < e; k++) {
      int2 p = pairs[k];
      acc = fmaf(__int_as_float(p.y), ego[(size_t)p.x * D + lane], acc);
    }
    side[(size_t)n * D + lane] = acc;
  }
}

// ===========================================================================
// Fallback atomic scatter (only if ws too small / N too big for CSR path)
// ===========================================================================
__global__ __launch_bounds__(256) void scatter_spmm(
    const int* __restrict__ rows, const int* __restrict__ cols,
    const float* __restrict__ vals, const float* __restrict__ ego,
    float* __restrict__ side, int nnz) {
  long long t = (long long)blockIdx.x * blockDim.x + threadIdx.x;
  int e = (int)(t >> 4);
  if (e >= nnz) return;
  int c4 = (int)(t & 15);
  int r = rows[e];
  int c = cols[e];
  float v = vals[e];
  const float4* src = (const float4*)(ego + (size_t)c * D);
  float4 x = src[c4];
  float* dst = side + (size_t)r * D + c4 * 4;
  atomicAdd(dst + 0, v * x.x);
  atomicAdd(dst + 1, v * x.y);
  atomicAdd(dst + 2, v * x.z);
  atomicAdd(dst + 3, v * x.w);
}

// ===========================================================================
// Per-node transform v3 (verified ~76 us): W columns in registers, LDS only
// for the per-node 512 B s/p broadcast vector. Next node's s/e prefetched.
// v5 (2 nodes/wave) REGRESSED 3x: >128 live VGPRs -> spill. Do not add
// per-wave state.
// ===========================================================================
__global__ __launch_bounds__(256, 2) void transform_nodes(
    float* __restrict__ ego, const float* __restrict__ side,
    const float* __restrict__ Wgc, const float* __restrict__ bgc,
    const float* __restrict__ Wbi, const float* __restrict__ bbi,
    unsigned short* __restrict__ ego16, int w16, int N) {
  __shared__ float sSP[4][2 * D];   // per-wave {s,p} interleaved (512 B/wave)

  int wave = threadIdx.x >> 6;
  int lane = threadIdx.x & 63;

  // W columns -> registers (coalesced loads, L2-hot after first block)
  float wg[D], wb[D];
#pragma unroll
  for (int i = 0; i < D; i++) {
    wg[i] = Wgc[i * D + lane];
    wb[i] = Wbi[i * D + lane];
  }
  float bg = bgc[lane];
  float bb = bbi[lane];

  int waveGlobal = blockIdx.x * 4 + wave;
  int nWaves = gridDim.x * 4;

  float2* spw = (float2*)sSP[wave];
  const float4* q = (const float4*)sSP[wave];

  int n = waveGlobal;
  float s = 0.f, e = 0.f;
  if (n < N) {
    s = side[(size_t)n * D + lane];
    e = ego[(size_t)n * D + lane];
  }
  for (; n < N; n += nWaves) {
    spw[lane] = make_float2(s, e * s);
    // prefetch next node while this node computes
    int nn = n + nWaves;
    float sN = 0.f, eN = 0.f;
    if (nn < N) {
      sN = side[(size_t)nn * D + lane];
      eN = ego[(size_t)nn * D + lane];
    }
    float ag0 = bg, ab0 = bb;
    float ag1 = 0.f, ab1 = 0.f, ag2 = 0.f, ab2 = 0.f, ag3 = 0.f, ab3 = 0.f;
#pragma unroll
    for (int j = 0; j < D / 2; j += 2) {
      float4 p0 = q[j];       // broadcast {s_2j, p_2j, s_2j+1, p_2j+1}
      float4 p1 = q[j + 1];   // broadcast {s_2j+2, p_2j+2, s_2j+3, p_2j+3}
      ag0 = fmaf(p0.x, wg[2 * j], ag0);
      ab0 = fmaf(p0.y, wb[2 * j], ab0);
      ag1 = fmaf(p0.z, wg[2 * j + 1], ag1);
      ab1 = fmaf(p0.w, wb[2 * j + 1], ab1);
      ag2 = fmaf(p1.x, wg[2 * j + 2], ag2);
      ab2 = fmaf(p1.y, wb[2 * j + 2], ab2);
      ag3 = fmaf(p1.z, wg[2 * j + 3], ag3);
      ab3 = fmaf(p1.w, wb[2 * j + 3], ab3);
    }
    float v = (ag0 + ag1 + ag2 + ag3) + (ab0 + ab1 + ab2 + ab3);
    v = v > 0.f ? v : NEG_SLOPE * v;
    ego[(size_t)n * D + lane] = v;
    if (w16) ego16[(size_t)n * D + lane] = f32_to_bf16(v);
    s = sN;
    e = eN;
  }
}

// ===========================================================================
// Gather one 64-wide slice of the three outputs into d_out
// ===========================================================================
__global__ __launch_bounds__(256) void gather_out(
    const float* __restrict__ ego, const int* __restrict__ u,
    const int* __restrict__ iidx, const int* __restrict__ jidx,
    float* __restrict__ out, int n_users, int B, int slice, int normalize) {
  int r = blockIdx.x * 4 + (threadIdx.x >> 6);
  int lane = threadIdx.x & 63;
  if (r >= 3 * B) return;
  int which = r / B;
  int b = r - which * B;
  int n = (which == 0) ? u[b] : (n_users + ((which == 1) ? iidx[b] : jidx[b]));
  float v = ego[(size_t)n * D + lane];
  if (normalize) {
    float sq = v * v;
#pragma unroll
    for (int off = 32; off > 0; off >>= 1) sq += __shfl_xor(sq, off);
    float norm = sqrtf(sq);
    v = v / fmaxf(norm, EPS);
  }
  out[(size_t)which * B * 256 + (size_t)b * 256 + slice * D + lane] = v;
}

// ===========================================================================
// Launch
// ===========================================================================
extern "C" void kernel_launch(void* const* d_in, const int* in_sizes, int n_in,
                              void* d_out, int out_size, void* d_ws, size_t ws_size,
                              hipStream_t stream) {
  const int*   rows     = (const int*)d_in[0];
  const int*   cols     = (const int*)d_in[1];
  const float* vals     = (const float*)d_in[2];
  const float* user_emb = (const float*)d_in[3];
  const float* item_emb = (const float*)d_in[4];
  const float* W_gc     = (const float*)d_in[5];
  const float* b_gc     = (const float*)d_in[6];
  const float* W_bi     = (const float*)d_in[7];
  const float* b_bi     = (const float*)d_in[8];
  const int*   u        = (const int*)d_in[9];
  const int*   iidx     = (const int*)d_in[10];
  const int*   jidx     = (const int*)d_in[11];

  int nnz     = in_sizes[0];
  int n_users = in_sizes[3] / D;
  int n_items = in_sizes[4] / D;
  int N       = n_users + n_items;
  int B       = in_sizes[9];
  float* out  = (float*)d_out;

  int nbc = (N + CROWS - 1) >> CB;

  // ---- workspace layout ----
  auto align256 = [](size_t x) { return (x + 255) & ~(size_t)255; };
  char* p = (char*)d_ws;
  size_t egoBytes  = align256((size_t)N * D * sizeof(float));
  size_t sideBytes = align256((size_t)N * D * sizeof(float));
  if ((size_t)nnz * sizeof(int2) > sideBytes)
    sideBytes = align256((size_t)nnz * sizeof(int2));  // bucketed aliases side

  float* ego  = (float*)p; p += egoBytes;
  float* side = (float*)p;
  int2* bucketed = (int2*)side;  // alias: dead before first spmm use of side
  p += sideBytes;
  int* row_ptr = (int*)p; p += align256((size_t)(N + 1) * sizeof(int));
  int* bcount  = (int*)p; p += align256((size_t)(nbc + 1) * sizeof(int));
  int* bbase   = (int*)p; p += align256((size_t)(nbc + 1) * sizeof(int));
  int* bcursor = (int*)p; p += align256((size_t)(nbc + 1) * sizeof(int));
  int2* pairs  = (int2*)p; p += align256((size_t)nnz * sizeof(int2));
  size_t need_csr = (size_t)(p - (char*)d_ws);
  unsigned short* ego16 = (unsigned short*)p;
  p += align256((size_t)N * D * sizeof(unsigned short));
  size_t need_16 = (size_t)(p - (char*)d_ws);

  int mode  = (ws_size >= need_csr && N <= (1 << 20) && nbc <= NBC_MAX) ? 0 : 2;
  int use16 = (mode == 0 && ws_size >= need_16) ? 1 : 0;

  // ego = concat(user_emb, item_emb) (+ bf16 mirror) in one pass
  int nU4 = n_users * D / 4;
  int nT4 = N * D / 4;
  init_ego<<<(nT4 + 255) / 256, 256, 0, stream>>>(user_emb, item_emb, ego,
                                                  ego16, nU4, nT4, use16);

  if (mode == 0) {
    hipMemsetAsync(bcount, 0, (size_t)nbc * sizeof(int), stream);
    hist_coarse<<<256, 256, 0, stream>>>(rows, bcount, nnz, nbc);
    scan_buckets<<<1, 256, 0, stream>>>(bcount, bbase, bcursor, nbc, nnz,
                                        row_ptr, N);
    int ntiles = (nnz + TILE_E - 1) / TILE_E;
    scatter_ranked<<<ntiles, 256, 0, stream>>>(rows, cols, vals, bcursor,
                                               bucketed, nnz, nbc);
    sort_csr<<<nbc, 256, 0, stream>>>(bucketed, bbase, row_ptr, pairs, N);
  }

  // slice 0: raw embeddings
  int gblocks = (3 * B + 3) / 4;
  gather_out<<<gblocks, 256, 0, stream>>>(ego, u, iidx, jidx, out, n_users, B,
                                          0, 0);

  long long sthreads = (long long)nnz * 16;
  int sblocks = (int)((sthreads + 255) / 256);

  for (int k = 0; k < 3; k++) {
    if (mode == 0) {
      if (use16)
        spmm_gather_bf16<<<2048, 256, 0, stream>>>(row_ptr, pairs, ego16, side,
                                                   N);
      else
        spmm_gather_packed<<<2048, 256, 0, stream>>>(row_ptr, pairs, ego, side,
                                                     N);
    } else {
      hipMemsetAsync(side, 0, (size_t)N * D * sizeof(float), stream);
      scatter_spmm<<<sblocks, 256, 0, stream>>>(rows, cols, vals, ego, side,
                                                nnz);
    }
    // ego16 mirror only needed while another spmm follows (k<2)
    transform_nodes<<<2048, 256, 0, stream>>>(
        ego, side, W_gc + (size_t)k * D * D, b_gc + (size_t)k * D,
        W_bi + (size_t)k * D * D, b_bi + (size_t)k * D, ego16,
        use16 && (k < 2), N);
    gather_out<<<gblocks, 256, 0, stream>>>(ego, u, iidx, jidx, out, n_users,
                                            B, k + 1, 1);
  }
}